// Round 2
// baseline (114.764 us; speedup 1.0000x reference)
//
#include <hip/hip_runtime.h>
#include <hip/hip_bf16.h>

// MVAS: multi-view routed window attention.
// cv: (1,128,128,256) f32   mv: (1,4,128,128,256) f32   out: (1,128,128,256) f32
// 64 windows (8x8) of 16x16 px; 8 heads x 32ch; route top-4 of 256 (4 views x 64 win).

typedef __attribute__((ext_vector_type(4))) float f32x4;
typedef __attribute__((ext_vector_type(8))) short s16x8;
typedef __attribute__((ext_vector_type(4))) short s16x4;

#define SCALE 0.0625f                      // 256^-0.5
#define LOG2E 1.44269504088896340736f

__device__ inline short f2bf(float x) {
  union { __hip_bfloat16 h; short s; } u;
  u.h = __float2bfloat16(x);
  return u.s;
}

// ---------------- kernel 1: window means (fp32) ----------------
// 320 blocks x 1024 threads; thread (pq, c) sums 64 px of channel c; LDS reduce.
__global__ __launch_bounds__(1024) void k_means(const float* __restrict__ cv,
                                                const float* __restrict__ mv,
                                                float* __restrict__ qwin,
                                                float* __restrict__ kwin) {
  __shared__ float sm[4][256];
  int b = blockIdx.x;
  int c = threadIdx.x & 255;
  int pq = threadIdx.x >> 8;
  const float* base;
  float* dst;
  if (b < 64) {
    base = cv + ((size_t)((b >> 3) * 16) * 128 + (b & 7) * 16) * 256;
    dst = qwin + b * 256;
  } else {
    int r = b - 64;
    base = mv + (size_t)(r >> 6) * (128 * 128 * 256)
         + ((size_t)(((r >> 3) & 7) * 16) * 128 + (r & 7) * 16) * 256;
    dst = kwin + r * 256;
  }
  float s = 0.f;
  for (int k = 0; k < 64; ++k) {
    int px = pq * 64 + k;
    s += base[((px >> 4) * 128 + (px & 15)) * 256 + c];
  }
  sm[pq][c] = s;
  __syncthreads();
  if (pq == 0)
    dst[c] = (sm[0][c] + sm[1][c] + sm[2][c] + sm[3][c]) * (1.f / 256.f);
}

// ---------------- kernel 2: routing logits + serial top-4 ----------------
__global__ __launch_bounds__(256) void k_route(const float* __restrict__ qwin,
                                               const float* __restrict__ kwin,
                                               int* __restrict__ ridx) {
  __shared__ float qrow[256];
  __shared__ float sv[256];
  int p = blockIdx.x, t = threadIdx.x;
  qrow[t] = qwin[p * 256 + t] * SCALE;
  __syncthreads();
  const f32x4* kr = reinterpret_cast<const f32x4*>(kwin + t * 256);
  float dot = 0.f;
#pragma unroll 4
  for (int c4 = 0; c4 < 64; ++c4) {
    f32x4 kv = kr[c4];
    dot += qrow[c4 * 4 + 0] * kv[0] + qrow[c4 * 4 + 1] * kv[1]
         + qrow[c4 * 4 + 2] * kv[2] + qrow[c4 * 4 + 3] * kv[3];
  }
  sv[t] = dot;
  __syncthreads();
  // serial top-4 by thread 0: strict > keeps lowest index on ties (lax.top_k)
  if (t == 0) {
    for (int k = 0; k < 4; ++k) {
      float bv = sv[0];
      int bi = 0;
      for (int j = 1; j < 256; ++j)
        if (sv[j] > bv) { bv = sv[j]; bi = j; }
      ridx[p * 4 + k] = bi;
      sv[bi] = -3.0e38f;
    }
  }
}

// ---------------- kernel 3: MFMA attention ----------------
// block = (window p, head m); 4 waves x 64 q-rows. No-max softmax (logits bounded).
// KV LDS: [256 row][32 ch] bf16, 16B-slot swizzle slot^=(row>>2)&3.
// P LDS per wave: [64 q][32 kv] bf16, slot^=(q&3).
// All LDS phases barrier-separated (round-2 hardening vs replay divergence).
__global__ __launch_bounds__(256, 2) void k_attn(const float* __restrict__ cv,
                                                 const float* __restrict__ mv,
                                                 const int* __restrict__ ridx,
                                                 float* __restrict__ out) {
  __shared__ __align__(16) short kv_lds[256 * 32];
  __shared__ __align__(16) short p_lds[4 * 64 * 32];

  const int tid = threadIdx.x;
  const int lane = tid & 63, wv = tid >> 6;
  const int g = lane >> 4, c16 = lane & 15;
  const int bid = blockIdx.x;
  const int p = bid >> 3, m = bid & 7;
  const int py = p >> 3, px = p & 7;

  // Q fragments (B-operand of QK^T): lane holds Q[q = qt*16+c16][ch = g*8..g*8+7]
  const float qs = SCALE * LOG2E;
  s16x8 qf[4];
#pragma unroll
  for (int qt = 0; qt < 4; ++qt) {
    const float* qp = cv + ((size_t)((py * 16 + wv * 4 + qt) * 128) + px * 16 + c16) * 256
                         + m * 32 + g * 8;
    f32x4 a = *reinterpret_cast<const f32x4*>(qp);
    f32x4 b = *reinterpret_cast<const f32x4*>(qp + 4);
    s16x8 q8;
    q8[0] = f2bf(a[0] * qs); q8[1] = f2bf(a[1] * qs);
    q8[2] = f2bf(a[2] * qs); q8[3] = f2bf(a[3] * qs);
    q8[4] = f2bf(b[0] * qs); q8[5] = f2bf(b[1] * qs);
    q8[6] = f2bf(b[2] * qs); q8[7] = f2bf(b[3] * qs);
    qf[qt] = q8;
  }

  f32x4 accO[4][2];
  float lsum[4];
#pragma unroll
  for (int qt = 0; qt < 4; ++qt) {
    lsum[qt] = 0.f;
    accO[qt][0] = f32x4{0.f, 0.f, 0.f, 0.f};
    accO[qt][1] = f32x4{0.f, 0.f, 0.f, 0.f};
  }
  const f32x4 zf = {0.f, 0.f, 0.f, 0.f};
  short* pw_lds = p_lds + wv * (64 * 32);

  for (int w = 0; w < 4; ++w) {
    // ---- stage routed KV window (shared across K and V: reference reuses k_sel) ----
    // (end-of-step barrier below guarantees all reads of window w-1 are done)
    {
      int r = ridx[p * 4 + w];
      int vv = r >> 6, pw = r & 63;
      const float* srcb = mv + (size_t)vv * (128 * 128 * 256)
                        + ((size_t)((pw >> 3) * 16) * 128 + (pw & 7) * 16) * 256 + m * 32;
#pragma unroll
      for (int i = 0; i < 8; ++i) {
        int u = i * 256 + tid;
        int pxl = u >> 3, quad = u & 7;
        f32x4 d = *reinterpret_cast<const f32x4*>(
            srcb + ((pxl >> 4) * 128 + (pxl & 15)) * 256 + quad * 4);
        s16x4 sv4;
        sv4[0] = f2bf(d[0]); sv4[1] = f2bf(d[1]);
        sv4[2] = f2bf(d[2]); sv4[3] = f2bf(d[3]);
        int slot = (quad >> 1) ^ ((pxl >> 2) & 3);
        *reinterpret_cast<s16x4*>(&kv_lds[pxl * 32 + (slot << 3) + (quad & 1) * 4]) = sv4;
      }
    }
    __syncthreads();
    // ---- 8 steps of 32 kv rows, phases barrier-separated ----
    for (int s = 0; s < 8; ++s) {
      // S^T = mfma(K, Q): lane holds S[kv = kt*16+4g+r][q = qt*16+c16]; exp2; pack to P LDS
#pragma unroll
      for (int kt = 0; kt < 2; ++kt) {
        int krow = s * 32 + kt * 16 + c16;
        s16x8 kf = *reinterpret_cast<const s16x8*>(
            &kv_lds[krow * 32 + ((g ^ ((krow >> 2) & 3)) << 3)]);
#pragma unroll
        for (int qt = 0; qt < 4; ++qt) {
          f32x4 st = __builtin_amdgcn_mfma_f32_16x16x32_bf16(kf, qf[qt], zf, 0, 0, 0);
          float p0 = exp2f(st[0]), p1 = exp2f(st[1]), p2 = exp2f(st[2]), p3 = exp2f(st[3]);
          lsum[qt] += (p0 + p1) + (p2 + p3);
          s16x4 pk;
          pk[0] = f2bf(p0); pk[1] = f2bf(p1); pk[2] = f2bf(p2); pk[3] = f2bf(p3);
          int q = qt * 16 + c16;
          int slot = (2 * kt + (g >> 1)) ^ (q & 3);
          *reinterpret_cast<s16x4*>(&pw_lds[q * 32 + (slot << 3) + (g & 1) * 4]) = pk;
        }
      }
      __syncthreads();   // P fully written before any PV read
      // V^T A-fragments: lane holds V[kv = s*32+8g+jj][ch = mt*16 + c16]
      s16x8 vf0, vf1;
#pragma unroll
      for (int jj = 0; jj < 8; ++jj) {
        int row = s * 32 + 8 * g + jj;
        int rsw = (row >> 2) & 3;
        vf0[jj] = kv_lds[row * 32 + (((c16 >> 3) ^ rsw) << 3) + (c16 & 7)];
        vf1[jj] = kv_lds[row * 32 + ((((c16 >> 3) + 2) ^ rsw) << 3) + (c16 & 7)];
      }
      // O^T += mfma(V^T, P^T)
#pragma unroll
      for (int qt = 0; qt < 4; ++qt) {
        int q = qt * 16 + c16;
        s16x8 pf = *reinterpret_cast<const s16x8*>(
            &pw_lds[q * 32 + ((g ^ (q & 3)) << 3)]);
        accO[qt][0] = __builtin_amdgcn_mfma_f32_16x16x32_bf16(vf0, pf, accO[qt][0], 0, 0, 0);
        accO[qt][1] = __builtin_amdgcn_mfma_f32_16x16x32_bf16(vf1, pf, accO[qt][1], 0, 0, 0);
      }
      __syncthreads();   // all PV reads done before next P-write / next staging
    }
  }

  // ---- epilogue: reduce l across the 4 lane-groups, normalize, store ----
#pragma unroll
  for (int qt = 0; qt < 4; ++qt) {
    float l = lsum[qt];
    l += __shfl_xor(l, 16, 64);
    l += __shfl_xor(l, 32, 64);
    float rl = 1.f / l;
#pragma unroll
    for (int mt = 0; mt < 2; ++mt) {
      f32x4 o = accO[qt][mt];
      o[0] *= rl; o[1] *= rl; o[2] *= rl; o[3] *= rl;
      float* op = out + ((size_t)((py * 16 + wv * 4 + qt) * 128) + px * 16 + c16) * 256
                      + m * 32 + mt * 16 + g * 4;
      *reinterpret_cast<f32x4*>(op) = o;
    }
  }
}

extern "C" void kernel_launch(void* const* d_in, const int* in_sizes, int n_in,
                              void* d_out, int out_size, void* d_ws, size_t ws_size,
                              hipStream_t stream) {
  const float* cv = (const float*)d_in[0];
  const float* mv = (const float*)d_in[1];
  float* out = (float*)d_out;

  float* qwin = (float*)d_ws;                 // 64*256 f32
  float* kwin = qwin + 64 * 256;              // 256*256 f32
  int* ridx = (int*)(kwin + 256 * 256);       // 64*4 i32

  k_means<<<320, 1024, 0, stream>>>(cv, mv, qwin, kwin);
  k_route<<<64, 256, 0, stream>>>(qwin, kwin, ridx);
  k_attn<<<512, 256, 0, stream>>>(cv, mv, ridx, out);
}

// Round 4
// 109.118 us; speedup vs baseline: 1.0517x; 1.0517x over previous
//
#include <hip/hip_runtime.h>
#include <hip/hip_bf16.h>

// MVAS: multi-view routed window attention.
// cv: (1,128,128,256) f32   mv: (1,4,128,128,256) f32   out: (1,128,128,256) f32
// 64 windows (8x8) of 16x16 px; 8 heads x 32ch; route top-4 of 256 (4 views x 64 win).

typedef __attribute__((ext_vector_type(4))) float f32x4;
typedef __attribute__((ext_vector_type(8))) short s16x8;
typedef __attribute__((ext_vector_type(4))) short s16x4;
typedef __attribute__((ext_vector_type(2))) unsigned u32x2;
typedef __attribute__((ext_vector_type(4))) unsigned u32x4;

#define SCALE 0.0625f                      // 256^-0.5
#define LOG2E 1.44269504088896340736f

__device__ inline unsigned cvt_pk_bf16(float lo, float hi) {
  unsigned r;
  asm("v_cvt_pk_bf16_f32 %0, %1, %2" : "=v"(r) : "v"(lo), "v"(hi));
  return r;
}

// ---------------- kernel 1: window means ----------------
// 1280 blocks x 256 thr: block = (window-of-320, ch-quarter); thread (pq, c64).
__global__ __launch_bounds__(256) void k_means(const float* __restrict__ cv,
                                               const float* __restrict__ mv,
                                               float* __restrict__ qwin,
                                               float* __restrict__ kwin) {
  __shared__ float sm[4][64];
  int wi = blockIdx.x >> 2, cq = blockIdx.x & 3;
  int pq = threadIdx.x >> 6, cl = threadIdx.x & 63;
  int c = cq * 64 + cl;
  const float* base;
  float* dst;
  if (wi < 64) {
    base = cv + ((size_t)((wi >> 3) * 16) * 128 + (wi & 7) * 16) * 256;
    dst = qwin + wi * 256;
  } else {
    int r = wi - 64;
    base = mv + (size_t)(r >> 6) * (128 * 128 * 256)
         + ((size_t)(((r >> 3) & 7) * 16) * 128 + (r & 7) * 16) * 256;
    dst = kwin + r * 256;
  }
  float s = 0.f;
  for (int k = 0; k < 64; ++k) {
    int px = pq * 64 + k;
    s += base[((px >> 4) * 128 + (px & 15)) * 256 + c];
  }
  sm[pq][cl] = s;
  __syncthreads();
  if (pq == 0)
    dst[c] = (sm[0][cl] + sm[1][cl] + sm[2][cl] + sm[3][cl]) * (1.f / 256.f);
}

// ---------------- kernel 2: routing logits + top-4 (parallel argmax) ----------------
__global__ __launch_bounds__(256) void k_route(const float* __restrict__ qwin,
                                               const float* __restrict__ kwin,
                                               int* __restrict__ ridx) {
  __shared__ float qrow[256];
  __shared__ float sv[256];
  __shared__ float wbv[4];
  __shared__ int wbi[4];
  int p = blockIdx.x, t = threadIdx.x;
  qrow[t] = qwin[p * 256 + t] * SCALE;
  __syncthreads();
  const f32x4* kr = reinterpret_cast<const f32x4*>(kwin + t * 256);
  float dot = 0.f;
#pragma unroll 4
  for (int c4 = 0; c4 < 64; ++c4) {
    f32x4 kv = kr[c4];
    dot += qrow[c4 * 4 + 0] * kv[0] + qrow[c4 * 4 + 1] * kv[1]
         + qrow[c4 * 4 + 2] * kv[2] + qrow[c4 * 4 + 3] * kv[3];
  }
  sv[t] = dot;
  __syncthreads();
  // 4 argmax rounds; strict-> / lower-index tie-break = lax.top_k set semantics
  for (int k = 0; k < 4; ++k) {
    float v = sv[t];
    int ii = t;
#pragma unroll
    for (int off = 32; off > 0; off >>= 1) {
      float ov = __shfl_down(v, off, 64);
      int oi = __shfl_down(ii, off, 64);
      if (ov > v || (ov == v && oi < ii)) { v = ov; ii = oi; }
    }
    if ((t & 63) == 0) { wbv[t >> 6] = v; wbi[t >> 6] = ii; }
    __syncthreads();
    if (t == 0) {
      float bv = wbv[0]; int bi = wbi[0];
      for (int j = 1; j < 4; ++j)
        if (wbv[j] > bv || (wbv[j] == bv && wbi[j] < bi)) { bv = wbv[j]; bi = wbi[j]; }
      ridx[p * 4 + k] = bi;
      sv[bi] = -3.0e38f;
    }
    __syncthreads();
  }
}

// ---------------- kernel 3: MFMA attention ----------------
// block = (window p, head m): 8 waves x 32 q-rows. No-max softmax (logits bounded).
// kv_lds: subtiled [kv/4][ch/16][4][16] bf16 -> conflict-free b128 K-rows;
//         V via scalar u16 column reads (4-way conflict, known-correct pattern).
// p_lds: per-wave [32 q][32 kv] bf16, 16B slots XOR-swizzled by (q&3).
// Block barriers ONLY around staging (kv_lds read-only during steps; P per-wave).
__global__ __launch_bounds__(512, 4) void k_attn(const float* __restrict__ cv,
                                                 const float* __restrict__ mv,
                                                 const int* __restrict__ ridx,
                                                 float* __restrict__ out) {
  __shared__ __align__(16) short kv_lds[256 * 32];
  __shared__ __align__(16) short p_lds[8 * 32 * 32];

  const int tid = threadIdx.x;
  const int lane = tid & 63, wv = tid >> 6;
  const int g = lane >> 4, c16 = lane & 15;
  const int p = blockIdx.x >> 3, m = blockIdx.x & 7;
  const int py = p >> 3, px = p & 7;

  const int4 ridx4 = *reinterpret_cast<const int4*>(ridx + p * 4);

  // Q fragments (B-operand of QK^T): lane holds Q[q = qt*16+c16][ch = g*8..g*8+7]
  const float qs = SCALE * LOG2E;
  s16x8 qf[2];
#pragma unroll
  for (int qt = 0; qt < 2; ++qt) {
    const float* qp = cv + ((size_t)((py * 16 + wv * 2 + qt) * 128) + px * 16 + c16) * 256
                         + m * 32 + g * 8;
    f32x4 a = *reinterpret_cast<const f32x4*>(qp);
    f32x4 b = *reinterpret_cast<const f32x4*>(qp + 4);
    union { u32x4 u; s16x8 s; } cu;
    cu.u[0] = cvt_pk_bf16(a[0] * qs, a[1] * qs);
    cu.u[1] = cvt_pk_bf16(a[2] * qs, a[3] * qs);
    cu.u[2] = cvt_pk_bf16(b[0] * qs, b[1] * qs);
    cu.u[3] = cvt_pk_bf16(b[2] * qs, b[3] * qs);
    qf[qt] = cu.s;
  }

  f32x4 accO[2][2];
  float lsum[2];
#pragma unroll
  for (int qt = 0; qt < 2; ++qt) {
    lsum[qt] = 0.f;
    accO[qt][0] = f32x4{0.f, 0.f, 0.f, 0.f};
    accO[qt][1] = f32x4{0.f, 0.f, 0.f, 0.f};
  }
  const f32x4 zf = {0.f, 0.f, 0.f, 0.f};
  short* pw = p_lds + wv * (32 * 32);

  for (int w = 0; w < 4; ++w) {
    if (w) __syncthreads();  // all reads of window w-1 done before overwrite
    {
      int r = (&ridx4.x)[w];
      const float* srcb = mv + (size_t)(r >> 6) * (128 * 128 * 256)
                        + ((size_t)(((r >> 3) & 7) * 16) * 128 + (r & 7) * 16) * 256 + m * 32;
#pragma unroll
      for (int i = 0; i < 4; ++i) {
        int u = i * 512 + tid;
        int pxl = u >> 3, quad = u & 7;
        f32x4 d = *reinterpret_cast<const f32x4*>(
            srcb + ((pxl >> 4) * 128 + (pxl & 15)) * 256 + quad * 4);
        u32x2 pk;
        pk[0] = cvt_pk_bf16(d[0], d[1]);
        pk[1] = cvt_pk_bf16(d[2], d[3]);
        // subtiled addr: [pxl>>2][quad>>2][pxl&3][(quad&3)*4]
        int off = (pxl >> 2) * 128 + (quad >> 2) * 64 + (pxl & 3) * 16 + (quad & 3) * 4;
        *reinterpret_cast<u32x2*>(&kv_lds[off]) = pk;
      }
    }
    __syncthreads();

    for (int s = 0; s < 8; ++s) {
      // ---- QK phase: S^T = mfma(K, Q); lane gets S[kv=kt*16+g*4+r][q=qt*16+c16] ----
#pragma unroll
      for (int kt = 0; kt < 2; ++kt) {
        int krow = s * 32 + kt * 16 + c16;
        const s16x8 kf = *reinterpret_cast<const s16x8*>(
            &kv_lds[(krow >> 2) * 128 + (g >> 1) * 64 + (krow & 3) * 16 + (g & 1) * 8]);
#pragma unroll
        for (int qt = 0; qt < 2; ++qt) {
          f32x4 st = __builtin_amdgcn_mfma_f32_16x16x32_bf16(kf, qf[qt], zf, 0, 0, 0);
          float p0 = exp2f(st[0]), p1 = exp2f(st[1]), p2 = exp2f(st[2]), p3 = exp2f(st[3]);
          lsum[qt] += (p0 + p1) + (p2 + p3);
          u32x2 pk;
          pk[0] = cvt_pk_bf16(p0, p1);
          pk[1] = cvt_pk_bf16(p2, p3);
          int q = qt * 16 + c16;
          int slot = (2 * kt + (g >> 1)) ^ (q & 3);
          *reinterpret_cast<u32x2*>(&pw[q * 32 + (slot << 3) + (g & 1) * 4]) = pk;
        }
      }
      // wave-internal fence: P writes complete (DS in-order) + no compiler reorder
      asm volatile("s_waitcnt lgkmcnt(0)" ::: "memory");
      // ---- PV phase: V^T columns via scalar u16 reads from subtiled layout ----
      // V0[j] = V[kv = s*32+8g+j][ch = c16], V1[j] = same at ch 16+c16.
      s16x8 V0, V1;
      {
        int r0 = s * 8 + 2 * g;
#pragma unroll
        for (int j = 0; j < 8; ++j) {
          int a = (r0 + (j >> 2)) * 128 + (j & 3) * 16 + c16;
          V0[j] = kv_lds[a];
          V1[j] = kv_lds[a + 64];
        }
      }
#pragma unroll
      for (int qt = 0; qt < 2; ++qt) {
        int q = qt * 16 + c16;
        const s16x8 pf = *reinterpret_cast<const s16x8*>(
            &pw[q * 32 + ((g ^ (q & 3)) << 3)]);
        accO[qt][0] = __builtin_amdgcn_mfma_f32_16x16x32_bf16(V0, pf, accO[qt][0], 0, 0, 0);
        accO[qt][1] = __builtin_amdgcn_mfma_f32_16x16x32_bf16(V1, pf, accO[qt][1], 0, 0, 0);
      }
      asm volatile("" ::: "memory");  // P reads precede next step's P writes
    }
  }

  // ---- epilogue: reduce l across the 4 lane-groups, normalize, store ----
#pragma unroll
  for (int qt = 0; qt < 2; ++qt) {
    float l = lsum[qt];
    l += __shfl_xor(l, 16, 64);
    l += __shfl_xor(l, 32, 64);
    float rl = 1.f / l;
#pragma unroll
    for (int mt = 0; mt < 2; ++mt) {
      f32x4 o = accO[qt][mt];
      o[0] *= rl; o[1] *= rl; o[2] *= rl; o[3] *= rl;
      float* op = out + ((size_t)((py * 16 + wv * 2 + qt) * 128) + px * 16 + c16) * 256
                      + m * 32 + mt * 16 + g * 4;
      *reinterpret_cast<f32x4*>(op) = o;
    }
  }
}

extern "C" void kernel_launch(void* const* d_in, const int* in_sizes, int n_in,
                              void* d_out, int out_size, void* d_ws, size_t ws_size,
                              hipStream_t stream) {
  const float* cv = (const float*)d_in[0];
  const float* mv = (const float*)d_in[1];
  float* out = (float*)d_out;

  float* qwin = (float*)d_ws;                 // 64*256 f32
  float* kwin = qwin + 64 * 256;              // 256*256 f32
  int* ridx = (int*)(kwin + 256 * 256);       // 64*4 i32

  k_means<<<1280, 256, 0, stream>>>(cv, mv, qwin, kwin);
  k_route<<<64, 256, 0, stream>>>(qwin, kwin, ridx);
  k_attn<<<512, 512, 0, stream>>>(cv, mv, ridx, out);
}

// Round 5
// 87.041 us; speedup vs baseline: 1.3185x; 1.2536x over previous
//
#include <hip/hip_runtime.h>
#include <hip/hip_bf16.h>

// MVAS: multi-view routed window attention.
// cv: (1,128,128,256) f32   mv: (1,4,128,128,256) f32   out: (1,128,128,256) f32
// 64 windows (8x8) of 16x16 px; 8 heads x 32ch; route top-4 of 256 (4 views x 64 win).

typedef __attribute__((ext_vector_type(4))) float f32x4;
typedef __attribute__((ext_vector_type(8))) short s16x8;
typedef __attribute__((ext_vector_type(4))) short s16x4;
typedef __attribute__((ext_vector_type(2))) unsigned u32x2;
typedef __attribute__((ext_vector_type(4))) unsigned u32x4;

#define SCALE 0.0625f                      // 256^-0.5
#define LOG2E 1.44269504088896340736f

__device__ inline unsigned cvt_pk_bf16(float lo, float hi) {
  unsigned r;
  asm("v_cvt_pk_bf16_f32 %0, %1, %2" : "=v"(r) : "v"(lo), "v"(hi));
  return r;
}

// ---------------- kernel 1: window means ----------------
// 1280 blocks x 256 thr: block = (window-of-320, ch-quarter); thread (pq, c64).
__global__ __launch_bounds__(256) void k_means(const float* __restrict__ cv,
                                               const float* __restrict__ mv,
                                               float* __restrict__ qwin,
                                               float* __restrict__ kwin) {
  __shared__ float sm[4][64];
  int wi = blockIdx.x >> 2, cq = blockIdx.x & 3;
  int pq = threadIdx.x >> 6, cl = threadIdx.x & 63;
  int c = cq * 64 + cl;
  const float* base;
  float* dst;
  if (wi < 64) {
    base = cv + ((size_t)((wi >> 3) * 16) * 128 + (wi & 7) * 16) * 256;
    dst = qwin + wi * 256;
  } else {
    int r = wi - 64;
    base = mv + (size_t)(r >> 6) * (128 * 128 * 256)
         + ((size_t)(((r >> 3) & 7) * 16) * 128 + (r & 7) * 16) * 256;
    dst = kwin + r * 256;
  }
  float s = 0.f;
  for (int k = 0; k < 64; ++k) {
    int px = pq * 64 + k;
    s += base[((px >> 4) * 128 + (px & 15)) * 256 + c];
  }
  sm[pq][cl] = s;
  __syncthreads();
  if (pq == 0)
    dst[c] = (sm[0][cl] + sm[1][cl] + sm[2][cl] + sm[3][cl]) * (1.f / 256.f);
}

// ---------------- kernel 2: routing logits + top-4 (parallel argmax) ----------------
__global__ __launch_bounds__(256) void k_route(const float* __restrict__ qwin,
                                               const float* __restrict__ kwin,
                                               int* __restrict__ ridx) {
  __shared__ float qrow[256];
  __shared__ float sv[256];
  __shared__ float wbv[4];
  __shared__ int wbi[4];
  int p = blockIdx.x, t = threadIdx.x;
  qrow[t] = qwin[p * 256 + t] * SCALE;
  __syncthreads();
  const f32x4* kr = reinterpret_cast<const f32x4*>(kwin + t * 256);
  float dot = 0.f;
#pragma unroll 4
  for (int c4 = 0; c4 < 64; ++c4) {
    f32x4 kv = kr[c4];
    dot += qrow[c4 * 4 + 0] * kv[0] + qrow[c4 * 4 + 1] * kv[1]
         + qrow[c4 * 4 + 2] * kv[2] + qrow[c4 * 4 + 3] * kv[3];
  }
  sv[t] = dot;
  __syncthreads();
  // 4 argmax rounds; strict-> / lower-index tie-break = lax.top_k set semantics
  for (int k = 0; k < 4; ++k) {
    float v = sv[t];
    int ii = t;
#pragma unroll
    for (int off = 32; off > 0; off >>= 1) {
      float ov = __shfl_down(v, off, 64);
      int oi = __shfl_down(ii, off, 64);
      if (ov > v || (ov == v && oi < ii)) { v = ov; ii = oi; }
    }
    if ((t & 63) == 0) { wbv[t >> 6] = v; wbi[t >> 6] = ii; }
    __syncthreads();
    if (t == 0) {
      float bv = wbv[0]; int bi = wbi[0];
      for (int j = 1; j < 4; ++j)
        if (wbv[j] > bv || (wbv[j] == bv && wbi[j] < bi)) { bv = wbv[j]; bi = wbi[j]; }
      ridx[p * 4 + k] = bi;
      sv[bi] = -3.0e38f;
    }
    __syncthreads();
  }
}

// ---------------- kernel 3: MFMA attention ----------------
// block = (window p, head m): 4 FAT waves x 64 q-rows (qt=0..3) -> K/V LDS reads
// amortized over 4 q-tiles (r4's 8 thin waves doubled LDS traffic; reverted).
// kv_lds: subtiled [kv/4][ch-half][4][16] bf16 -> conflict-free b128 K-rows;
//         V via scalar u16 column reads (4-way conflict).
// p_lds: per-wave [64 q][32 kv] bf16, 16B slots XOR-swizzled by (q&3).
// Block barriers ONLY around staging; P round-trip uses wave-internal fences.
__global__ __launch_bounds__(256, 2) void k_attn(const float* __restrict__ cv,
                                                 const float* __restrict__ mv,
                                                 const int* __restrict__ ridx,
                                                 float* __restrict__ out) {
  __shared__ __align__(16) short kv_lds[256 * 32];
  __shared__ __align__(16) short p_lds[4 * 64 * 32];

  const int tid = threadIdx.x;
  const int lane = tid & 63, wv = tid >> 6;
  const int g = lane >> 4, c16 = lane & 15;
  const int p = blockIdx.x >> 3, m = blockIdx.x & 7;
  const int py = p >> 3, px = p & 7;

  const int4 ridx4 = *reinterpret_cast<const int4*>(ridx + p * 4);

  // Q fragments (B-operand of QK^T): lane holds Q[q = qt*16+c16][ch = g*8..g*8+7]
  const float qs = SCALE * LOG2E;
  s16x8 qf[4];
#pragma unroll
  for (int qt = 0; qt < 4; ++qt) {
    const float* qp = cv + ((size_t)((py * 16 + wv * 4 + qt) * 128) + px * 16 + c16) * 256
                         + m * 32 + g * 8;
    f32x4 a = *reinterpret_cast<const f32x4*>(qp);
    f32x4 b = *reinterpret_cast<const f32x4*>(qp + 4);
    union { u32x4 u; s16x8 s; } cu;
    cu.u[0] = cvt_pk_bf16(a[0] * qs, a[1] * qs);
    cu.u[1] = cvt_pk_bf16(a[2] * qs, a[3] * qs);
    cu.u[2] = cvt_pk_bf16(b[0] * qs, b[1] * qs);
    cu.u[3] = cvt_pk_bf16(b[2] * qs, b[3] * qs);
    qf[qt] = cu.s;
  }

  f32x4 accO[4][2];
  float lsum[4];
#pragma unroll
  for (int qt = 0; qt < 4; ++qt) {
    lsum[qt] = 0.f;
    accO[qt][0] = f32x4{0.f, 0.f, 0.f, 0.f};
    accO[qt][1] = f32x4{0.f, 0.f, 0.f, 0.f};
  }
  const f32x4 zf = {0.f, 0.f, 0.f, 0.f};
  short* pw = p_lds + wv * (64 * 32);

  for (int w = 0; w < 4; ++w) {
    if (w) __syncthreads();  // all reads of window w-1 done before overwrite
    {
      int r = (&ridx4.x)[w];
      const float* srcb = mv + (size_t)(r >> 6) * (128 * 128 * 256)
                        + ((size_t)(((r >> 3) & 7) * 16) * 128 + (r & 7) * 16) * 256 + m * 32;
#pragma unroll
      for (int i = 0; i < 8; ++i) {
        int u = i * 256 + tid;
        int pxl = u >> 3, quad = u & 7;
        f32x4 d = *reinterpret_cast<const f32x4*>(
            srcb + ((pxl >> 4) * 128 + (pxl & 15)) * 256 + quad * 4);
        u32x2 pk;
        pk[0] = cvt_pk_bf16(d[0], d[1]);
        pk[1] = cvt_pk_bf16(d[2], d[3]);
        // subtiled addr: [pxl>>2][quad>>2][pxl&3][(quad&3)*4]
        int off = (pxl >> 2) * 128 + (quad >> 2) * 64 + (pxl & 3) * 16 + (quad & 3) * 4;
        *reinterpret_cast<u32x2*>(&kv_lds[off]) = pk;
      }
    }
    __syncthreads();

    for (int s = 0; s < 8; ++s) {
      // ---- QK phase: S^T = mfma(K, Q); lane gets S[kv=kt*16+g*4+r][q=qt*16+c16] ----
#pragma unroll
      for (int kt = 0; kt < 2; ++kt) {
        int krow = s * 32 + kt * 16 + c16;
        const s16x8 kf = *reinterpret_cast<const s16x8*>(
            &kv_lds[(krow >> 2) * 128 + (g >> 1) * 64 + (krow & 3) * 16 + (g & 1) * 8]);
#pragma unroll
        for (int qt = 0; qt < 4; ++qt) {
          f32x4 st = __builtin_amdgcn_mfma_f32_16x16x32_bf16(kf, qf[qt], zf, 0, 0, 0);
          float p0 = exp2f(st[0]), p1 = exp2f(st[1]), p2 = exp2f(st[2]), p3 = exp2f(st[3]);
          lsum[qt] += (p0 + p1) + (p2 + p3);
          u32x2 pk;
          pk[0] = cvt_pk_bf16(p0, p1);
          pk[1] = cvt_pk_bf16(p2, p3);
          int q = qt * 16 + c16;
          int slot = (2 * kt + (g >> 1)) ^ (q & 3);
          *reinterpret_cast<u32x2*>(&pw[q * 32 + (slot << 3) + (g & 1) * 4]) = pk;
        }
      }
      // wave-internal fence: P writes complete (DS in-order) + no compiler reorder
      asm volatile("s_waitcnt lgkmcnt(0)" ::: "memory");
      __builtin_amdgcn_sched_barrier(0);
      // ---- PV phase: V^T columns via scalar u16 reads from subtiled layout ----
      // V0[j] = V[kv = s*32+8g+j][ch = c16], V1[j] = same at ch 16+c16.
      s16x8 V0, V1;
      {
        int r0 = s * 8 + 2 * g;
#pragma unroll
        for (int j = 0; j < 8; ++j) {
          int a = (r0 + (j >> 2)) * 128 + (j & 3) * 16 + c16;
          V0[j] = kv_lds[a];
          V1[j] = kv_lds[a + 64];
        }
      }
#pragma unroll
      for (int qt = 0; qt < 4; ++qt) {
        int q = qt * 16 + c16;
        const s16x8 pf = *reinterpret_cast<const s16x8*>(
            &pw[q * 32 + ((g ^ (q & 3)) << 3)]);
        accO[qt][0] = __builtin_amdgcn_mfma_f32_16x16x32_bf16(V0, pf, accO[qt][0], 0, 0, 0);
        accO[qt][1] = __builtin_amdgcn_mfma_f32_16x16x32_bf16(V1, pf, accO[qt][1], 0, 0, 0);
      }
      asm volatile("" ::: "memory");  // P reads precede next step's P writes
    }
  }

  // ---- epilogue: reduce l across the 4 lane-groups, normalize, store ----
#pragma unroll
  for (int qt = 0; qt < 4; ++qt) {
    float l = lsum[qt];
    l += __shfl_xor(l, 16, 64);
    l += __shfl_xor(l, 32, 64);
    float rl = 1.f / l;
#pragma unroll
    for (int mt = 0; mt < 2; ++mt) {
      f32x4 o = accO[qt][mt];
      o[0] *= rl; o[1] *= rl; o[2] *= rl; o[3] *= rl;
      float* op = out + ((size_t)((py * 16 + wv * 4 + qt) * 128) + px * 16 + c16) * 256
                      + m * 32 + mt * 16 + g * 4;
      *reinterpret_cast<f32x4*>(op) = o;
    }
  }
}

extern "C" void kernel_launch(void* const* d_in, const int* in_sizes, int n_in,
                              void* d_out, int out_size, void* d_ws, size_t ws_size,
                              hipStream_t stream) {
  const float* cv = (const float*)d_in[0];
  const float* mv = (const float*)d_in[1];
  float* out = (float*)d_out;

  float* qwin = (float*)d_ws;                 // 64*256 f32
  float* kwin = qwin + 64 * 256;              // 256*256 f32
  int* ridx = (int*)(kwin + 256 * 256);       // 64*4 i32

  k_means<<<1280, 256, 0, stream>>>(cv, mv, qwin, kwin);
  k_route<<<64, 256, 0, stream>>>(qwin, kwin, ridx);
  k_attn<<<512, 256, 0, stream>>>(cv, mv, ridx, out);
}